// Round 10
// baseline (542.053 us; speedup 1.0000x reference)
//
#include <hip/hip_runtime.h>

#define LROW    2904
#define PERIOD  24
#define CYC     121          // cycles; odd -> median = 0-indexed rank 60
#define NF      207
#define NB      64
#define NROWS   13248
#define NSLOT   61           // 121 keys packed 2/u32 (+1 sentinel halfword)
#define NT      256
#define LTILE   24
#define NLT     121
#define K2GRID  (NB * NLT)   // 7744
#define K2CHUNK (K2GRID / 8)
#define R13     (1.f / 13.f)

typedef unsigned short us2 __attribute__((ext_vector_type(2)));

__device__ __forceinline__ int clampi(int i) {
    return i < 0 ? 0 : (i >= LROW ? LROW - 1 : i);
}
// 16-bit fixed-point key: grid 2^-12, range [-8,8). Monotone (trunc+clamp).
__device__ __forceinline__ unsigned quantk(float d) {
    int ki = (int)fmaf(d, 4096.f, 32768.f);
    ki = ki < 0 ? 0 : (ki > 65535 ? 65535 : ki);
    return (unsigned)ki;
}
__device__ __forceinline__ float dqmid(unsigned k) {
    return ((float)(int)k - 32767.5f) * (1.f / 4096.f);
}

// Per-lane rank-60 select over 122 packed halfwords (121 real + 1 0xFFFF
// sentinel). Binary search on value: largest T with cnt_ge(T) >= 62 is the
// rank-60 key, recovered EXACTLY. 3 packed VOP3P ops/pair, no cross-lane.
__device__ __forceinline__ unsigned sel60(const unsigned (&K)[NSLOT]) {
    unsigned T = 0;
    const us2 one2 = __builtin_bit_cast(us2, 0x00010001u);
    for (int bit = 15; bit >= 0; --bit) {
        unsigned Tp = T | (1u << bit);
        unsigned tm32 = (Tp - 1u) | ((Tp - 1u) << 16);
        us2 tm2 = __builtin_bit_cast(us2, tm32);
        us2 acc = __builtin_bit_cast(us2, 0u);
        #pragma unroll
        for (int s = 0; s < NSLOT; ++s) {
            us2 kv = __builtin_bit_cast(us2, K[s]);
            us2 dd = __builtin_elementwise_sub_sat(kv, tm2);  // max(0, k-(Tp-1))
            us2 mm = __builtin_elementwise_min(dd, one2);     // 1 iff k >= Tp
            acc = acc + mm;                                   // <=61/half: no ovf
        }
        unsigned a = __builtin_bit_cast(unsigned, acc);
        int cnt = (int)(a & 0xFFFFu) + (int)(a >> 16);
        if (cnt >= 62) T = Tp;                                // per-lane cndmask
    }
    return T;
}

// ===== K0: stream x, rolling MA13 window, emit packed keys [b][p][61][f] ====
__global__ __launch_bounds__(256) void k_keys(const float* __restrict__ x,
                                              unsigned* __restrict__ keys) {
    const int b  = blockIdx.x;
    const int ft = blockIdx.y;
    const int wid = threadIdx.x >> 6, lane = threadIdx.x & 63;
    const int f  = ft * 64 + lane;
    const int fe = f < NF ? f : NF - 1;
    const bool fok = (f < NF);
    const int c0 = (wid == 0) ? 0 : 1 + 30 * wid;   // 0,31,61,91
    const int nc = (wid == 0) ? 31 : 30;
    const float* xb = x + (size_t)b * (LROW * NF) + fe;
    unsigned short* k16 = (unsigned short*)keys;

    // shift-register ring r[i] = x[clamp(l0-7+i)], l0 = c0*24; sum = SA[l0-1]
    float r[13];
    float sum = 0.f;
    const int l0 = c0 * PERIOD;
    #pragma unroll
    for (int i = 0; i < 13; ++i) {
        int l = l0 - 7 + i; if (l < 0) l = 0;
        r[i] = xb[(size_t)l * NF];
        sum += r[i];
    }
    unsigned pend[PERIOD];
    for (int cc = 0; cc < nc; ++cc) {
        const int c = c0 + cc;
        const int lb = c * PERIOD;
        const bool codd = (c & 1);
        const int slot = c >> 1;
        #pragma unroll
        for (int s = 0; s < PERIOD; ++s) {
            int ll = lb + s + 6; if (ll > LROW - 1) ll = LROW - 1;
            float xn = xb[(size_t)ll * NF];
            sum += xn - r[0];                  // sum = SA[lb+s]
            unsigned k = quantk(r[7] - sum * R13);   // r[7] = x[lb+s]
            size_t idx = ((size_t)(b * PERIOD + s) * NSLOT + slot) * NF + f;
            if (!codd) {
                pend[s] = k;
            } else if (fok) {
                if (cc == 0 && (c0 & 1))
                    k16[idx * 2 + 1] = (unsigned short)k;    // head: high half only
                else
                    keys[idx] = pend[s] | (k << 16);
            }
            #pragma unroll
            for (int i = 0; i < 12; ++i) r[i] = r[i + 1];
            r[12] = xn;
        }
    }
    // tail flush when segment ends on an even c
    const int cend = c0 + nc - 1;
    if (!(cend & 1) && fok) {
        const int slot = cend >> 1;
        #pragma unroll
        for (int s = 0; s < PERIOD; ++s) {
            size_t idx = ((size_t)(b * PERIOD + s) * NSLOT + slot) * NF + f;
            if (cend == CYC - 1) keys[idx] = pend[s] | 0xFFFF0000u;  // + sentinel
            else                 k16[idx * 2] = (unsigned short)pend[s];
        }
    }
}

// ===== K1: iter-0 medians, lane = feature, pure per-lane VALU select =======
__global__ __launch_bounds__(256) void k_med0(const unsigned* __restrict__ keys,
                                              unsigned short* __restrict__ med0key) {
    const int d  = blockIdx.x;                      // 1536 = 8*192, bijective
    const int bp = (d & 7) * 192 + (d >> 3);
    const int wid = threadIdx.x >> 6, lane = threadIdx.x & 63;
    const int f = wid * 64 + lane;
    const int fe = f < NF ? f : NF - 1;
    unsigned K[NSLOT];
    const unsigned* kp = keys + (size_t)bp * NSLOT * NF + fe;
    #pragma unroll
    for (int s = 0; s < NSLOT; ++s) K[s] = kp[s * NF];
    unsigned T = sel60(K);
    if (f < NF) med0key[(size_t)bp * NF + f] = (unsigned short)T;
}

// ===== K2: iter-1 edge phases (12): patch one key, re-select ===============
__global__ __launch_bounds__(256) void k_edge(const unsigned* __restrict__ keys,
                                              const unsigned short* __restrict__ med0key,
                                              float* __restrict__ medBedge) {
    const int d  = blockIdx.x;                      // 384 = 8*48, bijective
    const int bj = (d & 7) * 48 + (d >> 3);
    const int b = bj / 6, j = bj - 6 * b;
    const int wid = threadIdx.x >> 6, lane = threadIdx.x & 63;
    const int f = wid * 64 + lane;
    const int fe = f < NF ? f : NF - 1;

    float m0[PERIOD];
    #pragma unroll
    for (int p = 0; p < PERIOD; ++p)
        m0[p] = dqmid(med0key[(size_t)(b * PERIOD + p) * NF + fe]);

    // static-index W/edge sums via 6-way uniform branch (rule #20)
    float wA = 0.f, wB = 0.f, weA = 0.f, weB = 0.f;
    #pragma unroll
    for (int jj = 0; jj < 6; ++jj) if (jj == j) {
        #pragma unroll
        for (int t = 0; t < 13; ++t) {
            wA += m0[(jj + 18 + t) % 24];           // W[(pA+18)%24], pA=jj
            wB += m0[(jj + 12 + t) % 24];           // W[(pB+18)%24], pB=18+jj
        }
        #pragma unroll
        for (int t = -6; t <= 6; ++t) {
            int aa = jj + t;       if (aa < 0)  aa = 0;
            int bb = 18 + jj + t;  if (bb > 23) bb = 23;
            weA += m0[aa];                          // edge window, c=0 elem
            weB += m0[bb];                          // edge window, c=120 elem
        }
    }

    unsigned K[NSLOT];
    // phase A: p = j, edge element c=0 (slot 0, low half)
    {
        const unsigned* kp = keys + (size_t)(b * PERIOD + j) * NSLOT * NF + fe;
        #pragma unroll
        for (int s = 0; s < NSLOT; ++s) K[s] = kp[s * NF];
        unsigned kn = quantk(dqmid(K[0] & 0xFFFFu) + (weA - wA) * R13);
        K[0] = (K[0] & 0xFFFF0000u) | kn;
        unsigned T = sel60(K);
        if (f < NF) medBedge[(size_t)(b * 12 + j) * NF + f] = dqmid(T) + wA * R13;
    }
    // phase B: p = 18+j, edge element c=120 (slot 60, low half)
    {
        const unsigned* kp = keys + (size_t)(b * PERIOD + 18 + j) * NSLOT * NF + fe;
        #pragma unroll
        for (int s = 0; s < NSLOT; ++s) K[s] = kp[s * NF];
        unsigned kn = quantk(dqmid(K[60] & 0xFFFFu) + (weB - wB) * R13);
        K[60] = (K[60] & 0xFFFF0000u) | kn;
        unsigned T = sel60(K);
        if (f < NF) medBedge[(size_t)(b * 12 + 6 + j) * NF + f] = dqmid(T) + wB * R13;
    }
}

// ===== K3: assemble medB (interior translate) + W1 into ws[b][48][f] =======
__global__ __launch_bounds__(64) void k_final(const unsigned short* __restrict__ med0key,
                                              const float* __restrict__ medBedge,
                                              float* __restrict__ wsTab) {
    const int blk = blockIdx.x;                     // 256 = 64b * 4ft
    const int b = blk >> 2, ft = blk & 3;
    const int lane = threadIdx.x;
    const int f = ft * 64 + lane;
    const int fe = f < NF ? f : NF - 1;

    float m0[PERIOD], mB[PERIOD];
    #pragma unroll
    for (int p = 0; p < PERIOD; ++p)
        m0[p] = dqmid(med0key[(size_t)(b * PERIOD + p) * NF + fe]);
    float W0[PERIOD];
    {
        float s = 0.f;
        #pragma unroll
        for (int t = 0; t < 13; ++t) s += m0[t];
        W0[0] = s;
        #pragma unroll
        for (int q = 1; q < PERIOD; ++q)
            W0[q] = W0[q - 1] + m0[(q + 12) % 24] - m0[q - 1];
    }
    #pragma unroll
    for (int e = 0; e < 12; ++e) {
        int p = (e < 6) ? e : e + 12;
        mB[p] = medBedge[(size_t)(b * 12 + e) * NF + fe];
    }
    #pragma unroll
    for (int p = 6; p < 18; ++p) mB[p] = m0[p] + W0[p - 6] * R13;
    float W1[PERIOD];
    {
        float s = 0.f;
        #pragma unroll
        for (int t = 0; t < 13; ++t) s += mB[t];
        W1[0] = s;
        #pragma unroll
        for (int q = 1; q < PERIOD; ++q)
            W1[q] = W1[q - 1] + mB[(q + 12) % 24] - mB[q - 1];
    }
    if (f < NF) {
        #pragma unroll
        for (int p = 0; p < PERIOD; ++p) {
            wsTab[((size_t)b * 48 + p) * NF + f]      = mB[p];
            wsTab[((size_t)b * 48 + 24 + p) * NF + f] = W1[p];
        }
    }
}

// ===== K4: coalesced outputs (unchanged, proven) ===========================
__global__ __launch_bounds__(NT, 5) void stl_outputs(const float* __restrict__ x,
                                                     const float* __restrict__ ws,
                                                     float* __restrict__ out) {
    __shared__ float T[(LTILE + 12) * NF];

    const int d   = blockIdx.x;
    const int blk = (d & 7) * K2CHUNK + (d >> 3);
    const int b  = blk / NLT;
    const int kk = blk - b * NLT;
    const int l0 = kk * LTILE;
    const int t  = threadIdx.x;
    const float* xb = x + (size_t)b * (LROW * NF);

    if (kk != 0 && kk != NLT - 1) {
        const float2* s2 = (const float2*)(xb + (size_t)(l0 - 6) * NF);
        float2* t2 = (float2*)T;
        for (int i = t; i < (LTILE + 12) * NF / 2; i += NT) t2[i] = s2[i];
    } else {
        for (int i = t; i < (LTILE + 12) * NF; i += NT) {
            int lr = i / NF;
            int ff = i - lr * NF;
            T[i] = xb[(size_t)clampi(l0 - 6 + lr) * NF + ff];
        }
    }
    __syncthreads();

    if (t < NF) {
        float lm[PERIOD], wt[PERIOD];
        const float* wrow = ws + (size_t)b * 48 * NF + t;
        #pragma unroll
        for (int i = 0; i < PERIOD; ++i) lm[i] = wrow[i * NF];
        #pragma unroll
        for (int i = 0; i < PERIOD; ++i) wt[i] = wrow[(PERIOD + i) * NF];

        float s13 = 0.f;
        #pragma unroll
        for (int r = 0; r < 13; ++r) s13 += T[r * NF + t];

        const bool edgeLo = (kk == 0), edgeHi = (kk == NLT - 1);
        const size_t S = (size_t)NROWS * LROW;
        const size_t obase = (size_t)b * (LROW * NF) + (size_t)l0 * NF + (size_t)t;

        #pragma unroll
        for (int j = 0; j < LTILE; ++j) {
            float W = wt[(j + 18) % 24];
            if (edgeLo && j < 6) {
                float w = 0.f;
                #pragma unroll
                for (int jj = -6; jj <= 6; ++jj) { int m = j + jj; if (m < 0) m = 0; w += lm[m]; }
                W = w;
            }
            if (edgeHi && j >= 18) {
                float w = 0.f;
                #pragma unroll
                for (int jj = -6; jj <= 6; ++jj) { int m = j + jj; if (m > 23) m = 23; w += lm[m]; }
                W = w;
            }
            float tr = (s13 - W) * R13;
            float se = lm[j];
            float re = T[(j + 6) * NF + t] - tr - se;
            size_t o = obase + (size_t)(j * NF);
            __builtin_nontemporal_store(tr, &out[o]);
            __builtin_nontemporal_store(se, &out[S + o]);
            __builtin_nontemporal_store(re, &out[2 * S + o]);
            if (j < LTILE - 1)
                s13 += T[(j + 13) * NF + t] - T[j * NF + t];
        }
    }
}

extern "C" void kernel_launch(void* const* d_in, const int* in_sizes, int n_in,
                              void* d_out, int out_size, void* d_ws, size_t ws_size,
                              hipStream_t stream) {
    const float* x = (const float*)d_in[0];
    float* out = (float*)d_out;
    float* wsf = (float*)d_ws;
    (void)in_sizes; (void)n_in; (void)out_size; (void)ws_size;

    // workspace layout (floats): [wsTab 635904][keys 19401408 u32]
    //                            [medBedge 158976][med0key 317952 ushort]
    float*    wsTab    = wsf;
    unsigned* keys     = (unsigned*)(wsf + 635904);
    float*    medBedge = wsf + 635904 + 19401408;
    unsigned short* med0key = (unsigned short*)(wsf + 635904 + 19401408 + 158976);

    hipLaunchKernelGGL(k_keys,   dim3(NB, 4), dim3(256), 0, stream, x, keys);
    hipLaunchKernelGGL(k_med0,   dim3(NB * PERIOD), dim3(256), 0, stream, keys, med0key);
    hipLaunchKernelGGL(k_edge,   dim3(NB * 6), dim3(256), 0, stream, keys, med0key, medBedge);
    hipLaunchKernelGGL(k_final,  dim3(NB * 4), dim3(64), 0, stream, med0key, medBedge, wsTab);
    hipLaunchKernelGGL(stl_outputs, dim3(K2GRID), dim3(NT), 0, stream, x, wsTab, out);
}

// Round 11
// 344.711 us; speedup vs baseline: 1.5725x; 1.5725x over previous
//
#include <hip/hip_runtime.h>

#define LROW    2904
#define PERIOD  24
#define CYC     121          // cycles; odd -> median = 0-indexed rank 60
#define NF      207
#define NB      64
#define NROWS   13248
#define NSLOT   61           // 121 keys packed 2/u32 (+1 sentinel halfword)
#define NT      256
#define LTILE   24
#define NLT     121
#define K2GRID  (NB * NLT)   // 7744
#define K2CHUNK (K2GRID / 8)
#define R13     (1.f / 13.f)

typedef unsigned short us2 __attribute__((ext_vector_type(2)));

__device__ __forceinline__ int clampi(int i) {
    return i < 0 ? 0 : (i >= LROW ? LROW - 1 : i);
}
// 16-bit fixed-point key: grid 2^-12, range [-8,8). Monotone (trunc+clamp).
__device__ __forceinline__ unsigned quantk(float d) {
    int ki = (int)fmaf(d, 4096.f, 32768.f);
    ki = ki < 0 ? 0 : (ki > 65535 ? 65535 : ki);
    return (unsigned)ki;
}
__device__ __forceinline__ float dqmid(unsigned k) {
    return ((float)(int)k - 32767.5f) * (1.f / 4096.f);
}

// Per-lane rank-60 select over 122 packed halfwords (121 real + 1 0xFFFF
// sentinel). Binary search on value: largest T with cnt_ge(T) >= 62 is the
// rank-60 key, recovered EXACTLY. 3 packed VOP3P ops/pair, no cross-lane.
__device__ __forceinline__ unsigned sel60(const unsigned (&K)[NSLOT]) {
    unsigned T = 0;
    const us2 one2 = __builtin_bit_cast(us2, 0x00010001u);
    for (int bit = 15; bit >= 0; --bit) {
        unsigned Tp = T | (1u << bit);
        unsigned tm32 = (Tp - 1u) | ((Tp - 1u) << 16);
        us2 tm2 = __builtin_bit_cast(us2, tm32);
        us2 acc = __builtin_bit_cast(us2, 0u);
        #pragma unroll
        for (int s = 0; s < NSLOT; ++s) {
            us2 kv = __builtin_bit_cast(us2, K[s]);
            us2 dd = __builtin_elementwise_sub_sat(kv, tm2);  // max(0, k-(Tp-1))
            us2 mm = __builtin_elementwise_min(dd, one2);     // 1 iff k >= Tp
            acc = acc + mm;                                   // <=61/half: no ovf
        }
        unsigned a = __builtin_bit_cast(unsigned, acc);
        int cnt = (int)(a & 0xFFFFu) + (int)(a >> 16);
        if (cnt >= 62) T = Tp;                                // per-lane cndmask
    }
    return T;
}

// ===== K0: keys. One wave per (b, f-band, 4-cycle segment): 7936 blocks ====
// Segments start at even c -> each wave writes whole u32 slots (no halves).
__global__ __launch_bounds__(64) void k_keys(const float* __restrict__ x,
                                             unsigned* __restrict__ keys) {
    const int b   = blockIdx.x;
    const int ft  = blockIdx.y;
    const int seg = blockIdx.z;            // 0..30; seg<30: c in [4s,4s+4)
    const int lane = threadIdx.x;
    const int f  = ft * 64 + lane;
    const int fe = f < NF ? f : NF - 1;
    const bool fok = (f < NF);
    const int c0 = seg * 4;
    const float* xb = x + (size_t)b * (LROW * NF) + fe;

    // ring r[i] = x[clamp(l0-7+i)], l0 = c0*24; sum = SA[l0-1]
    float r[13];
    float sum = 0.f;
    const int l0 = c0 * PERIOD;
    #pragma unroll
    for (int i = 0; i < 13; ++i) {
        int l = l0 - 7 + i; if (l < 0) l = 0;
        r[i] = xb[(size_t)l * NF];
        sum += r[i];
    }
    unsigned pend[PERIOD];
    if (seg < 30) {
        #pragma unroll
        for (int cc = 0; cc < 4; ++cc) {           // cc parity compile-time
            const int c = c0 + cc;
            const int lb = c * PERIOD;
            const int slot = c >> 1;
            #pragma unroll
            for (int s = 0; s < PERIOD; ++s) {
                float xn = xb[(size_t)(lb + s + 6) * NF];   // max 2885 < LROW
                sum += xn - r[0];                  // sum = SA[lb+s]
                unsigned k = quantk(r[7] - sum * R13);      // r[7] = x[lb+s]
                if ((cc & 1) == 0) {
                    pend[s] = k;
                } else if (fok) {
                    keys[((size_t)(b * PERIOD + s) * NSLOT + slot) * NF + f]
                        = pend[s] | (k << 16);
                }
                #pragma unroll
                for (int i = 0; i < 12; ++i) r[i] = r[i + 1];
                r[12] = xn;
            }
        }
    } else {                                        // c = 120: slot 60 + sentinel
        const int lb = 120 * PERIOD;
        #pragma unroll
        for (int s = 0; s < PERIOD; ++s) {
            int ll = lb + s + 6; if (ll > LROW - 1) ll = LROW - 1;
            float xn = xb[(size_t)ll * NF];
            sum += xn - r[0];
            unsigned k = quantk(r[7] - sum * R13);
            if (fok)
                keys[((size_t)(b * PERIOD + s) * NSLOT + 60) * NF + f]
                    = k | 0xFFFF0000u;
            #pragma unroll
            for (int i = 0; i < 12; ++i) r[i] = r[i + 1];
            r[12] = xn;
        }
    }
}

// ===== K1: iter-0 medians, lane = feature, pure per-lane VALU select =======
__global__ __launch_bounds__(256) void k_med0(const unsigned* __restrict__ keys,
                                              unsigned short* __restrict__ med0key) {
    const int d  = blockIdx.x;                      // 1536 = 8*192, bijective
    const int bp = (d & 7) * 192 + (d >> 3);
    const int wid = threadIdx.x >> 6, lane = threadIdx.x & 63;
    const int f = wid * 64 + lane;
    const int fe = f < NF ? f : NF - 1;
    unsigned K[NSLOT];
    const unsigned* kp = keys + (size_t)bp * NSLOT * NF + fe;
    #pragma unroll
    for (int s = 0; s < NSLOT; ++s) K[s] = kp[s * NF];
    unsigned T = sel60(K);
    if (f < NF) med0key[(size_t)bp * NF + f] = (unsigned short)T;
}

// ===== K2: iter-1 edge phases (12): patch one key, re-select ===============
__global__ __launch_bounds__(256) void k_edge(const unsigned* __restrict__ keys,
                                              const unsigned short* __restrict__ med0key,
                                              float* __restrict__ medBedge) {
    const int d  = blockIdx.x;                      // 384 = 8*48, bijective
    const int bj = (d & 7) * 48 + (d >> 3);
    const int b = bj / 6, j = bj - 6 * b;
    const int wid = threadIdx.x >> 6, lane = threadIdx.x & 63;
    const int f = wid * 64 + lane;
    const int fe = f < NF ? f : NF - 1;

    float m0[PERIOD];
    #pragma unroll
    for (int p = 0; p < PERIOD; ++p)
        m0[p] = dqmid(med0key[(size_t)(b * PERIOD + p) * NF + fe]);

    // static-index W/edge sums via 6-way uniform branch (rule #20)
    float wA = 0.f, wB = 0.f, weA = 0.f, weB = 0.f;
    #pragma unroll
    for (int jj = 0; jj < 6; ++jj) if (jj == j) {
        #pragma unroll
        for (int t = 0; t < 13; ++t) {
            wA += m0[(jj + 18 + t) % 24];           // W[(pA+18)%24], pA=jj
            wB += m0[(jj + 12 + t) % 24];           // W[(pB+18)%24], pB=18+jj
        }
        #pragma unroll
        for (int t = -6; t <= 6; ++t) {
            int aa = jj + t;       if (aa < 0)  aa = 0;
            int bb = 18 + jj + t;  if (bb > 23) bb = 23;
            weA += m0[aa];                          // edge window, c=0 elem
            weB += m0[bb];                          // edge window, c=120 elem
        }
    }

    unsigned K[NSLOT];
    // phase A: p = j, edge element c=0 (slot 0, low half)
    {
        const unsigned* kp = keys + (size_t)(b * PERIOD + j) * NSLOT * NF + fe;
        #pragma unroll
        for (int s = 0; s < NSLOT; ++s) K[s] = kp[s * NF];
        unsigned kn = quantk(dqmid(K[0] & 0xFFFFu) + (weA - wA) * R13);
        K[0] = (K[0] & 0xFFFF0000u) | kn;
        unsigned T = sel60(K);
        if (f < NF) medBedge[(size_t)(b * 12 + j) * NF + f] = dqmid(T) + wA * R13;
    }
    // phase B: p = 18+j, edge element c=120 (slot 60, low half)
    {
        const unsigned* kp = keys + (size_t)(b * PERIOD + 18 + j) * NSLOT * NF + fe;
        #pragma unroll
        for (int s = 0; s < NSLOT; ++s) K[s] = kp[s * NF];
        unsigned kn = quantk(dqmid(K[60] & 0xFFFFu) + (weB - wB) * R13);
        K[60] = (K[60] & 0xFFFF0000u) | kn;
        unsigned T = sel60(K);
        if (f < NF) medBedge[(size_t)(b * 12 + 6 + j) * NF + f] = dqmid(T) + wB * R13;
    }
}

// ===== K3: assemble medB (interior translate) + W1 into ws[b][48][f] =======
__global__ __launch_bounds__(64) void k_final(const unsigned short* __restrict__ med0key,
                                              const float* __restrict__ medBedge,
                                              float* __restrict__ wsTab) {
    const int blk = blockIdx.x;                     // 256 = 64b * 4ft
    const int b = blk >> 2, ft = blk & 3;
    const int lane = threadIdx.x;
    const int f = ft * 64 + lane;
    const int fe = f < NF ? f : NF - 1;

    float m0[PERIOD], mB[PERIOD];
    #pragma unroll
    for (int p = 0; p < PERIOD; ++p)
        m0[p] = dqmid(med0key[(size_t)(b * PERIOD + p) * NF + fe]);
    float W0[PERIOD];
    {
        float s = 0.f;
        #pragma unroll
        for (int t = 0; t < 13; ++t) s += m0[t];
        W0[0] = s;
        #pragma unroll
        for (int q = 1; q < PERIOD; ++q)
            W0[q] = W0[q - 1] + m0[(q + 12) % 24] - m0[q - 1];
    }
    #pragma unroll
    for (int e = 0; e < 12; ++e) {
        int p = (e < 6) ? e : e + 12;
        mB[p] = medBedge[(size_t)(b * 12 + e) * NF + fe];
    }
    #pragma unroll
    for (int p = 6; p < 18; ++p) mB[p] = m0[p] + W0[p - 6] * R13;
    float W1[PERIOD];
    {
        float s = 0.f;
        #pragma unroll
        for (int t = 0; t < 13; ++t) s += mB[t];
        W1[0] = s;
        #pragma unroll
        for (int q = 1; q < PERIOD; ++q)
            W1[q] = W1[q - 1] + mB[(q + 12) % 24] - mB[q - 1];
    }
    if (f < NF) {
        #pragma unroll
        for (int p = 0; p < PERIOD; ++p) {
            wsTab[((size_t)b * 48 + p) * NF + f]      = mB[p];
            wsTab[((size_t)b * 48 + 24 + p) * NF + f] = W1[p];
        }
    }
}

// ===== K4: coalesced outputs (unchanged, proven) ===========================
__global__ __launch_bounds__(NT, 5) void stl_outputs(const float* __restrict__ x,
                                                     const float* __restrict__ ws,
                                                     float* __restrict__ out) {
    __shared__ float T[(LTILE + 12) * NF];

    const int d   = blockIdx.x;
    const int blk = (d & 7) * K2CHUNK + (d >> 3);
    const int b  = blk / NLT;
    const int kk = blk - b * NLT;
    const int l0 = kk * LTILE;
    const int t  = threadIdx.x;
    const float* xb = x + (size_t)b * (LROW * NF);

    if (kk != 0 && kk != NLT - 1) {
        const float2* s2 = (const float2*)(xb + (size_t)(l0 - 6) * NF);
        float2* t2 = (float2*)T;
        for (int i = t; i < (LTILE + 12) * NF / 2; i += NT) t2[i] = s2[i];
    } else {
        for (int i = t; i < (LTILE + 12) * NF; i += NT) {
            int lr = i / NF;
            int ff = i - lr * NF;
            T[i] = xb[(size_t)clampi(l0 - 6 + lr) * NF + ff];
        }
    }
    __syncthreads();

    if (t < NF) {
        float lm[PERIOD], wt[PERIOD];
        const float* wrow = ws + (size_t)b * 48 * NF + t;
        #pragma unroll
        for (int i = 0; i < PERIOD; ++i) lm[i] = wrow[i * NF];
        #pragma unroll
        for (int i = 0; i < PERIOD; ++i) wt[i] = wrow[(PERIOD + i) * NF];

        float s13 = 0.f;
        #pragma unroll
        for (int r = 0; r < 13; ++r) s13 += T[r * NF + t];

        const bool edgeLo = (kk == 0), edgeHi = (kk == NLT - 1);
        const size_t S = (size_t)NROWS * LROW;
        const size_t obase = (size_t)b * (LROW * NF) + (size_t)l0 * NF + (size_t)t;

        #pragma unroll
        for (int j = 0; j < LTILE; ++j) {
            float W = wt[(j + 18) % 24];
            if (edgeLo && j < 6) {
                float w = 0.f;
                #pragma unroll
                for (int jj = -6; jj <= 6; ++jj) { int m = j + jj; if (m < 0) m = 0; w += lm[m]; }
                W = w;
            }
            if (edgeHi && j >= 18) {
                float w = 0.f;
                #pragma unroll
                for (int jj = -6; jj <= 6; ++jj) { int m = j + jj; if (m > 23) m = 23; w += lm[m]; }
                W = w;
            }
            float tr = (s13 - W) * R13;
            float se = lm[j];
            float re = T[(j + 6) * NF + t] - tr - se;
            size_t o = obase + (size_t)(j * NF);
            __builtin_nontemporal_store(tr, &out[o]);
            __builtin_nontemporal_store(se, &out[S + o]);
            __builtin_nontemporal_store(re, &out[2 * S + o]);
            if (j < LTILE - 1)
                s13 += T[(j + 13) * NF + t] - T[j * NF + t];
        }
    }
}

extern "C" void kernel_launch(void* const* d_in, const int* in_sizes, int n_in,
                              void* d_out, int out_size, void* d_ws, size_t ws_size,
                              hipStream_t stream) {
    const float* x = (const float*)d_in[0];
    float* out = (float*)d_out;
    float* wsf = (float*)d_ws;
    (void)in_sizes; (void)n_in; (void)out_size; (void)ws_size;

    // workspace layout (floats): [wsTab 635904][keys 19401408 u32]
    //                            [medBedge 158976][med0key 317952 ushort]
    float*    wsTab    = wsf;
    unsigned* keys     = (unsigned*)(wsf + 635904);
    float*    medBedge = wsf + 635904 + 19401408;
    unsigned short* med0key = (unsigned short*)(wsf + 635904 + 19401408 + 158976);

    hipLaunchKernelGGL(k_keys,   dim3(NB, 4, 31), dim3(64), 0, stream, x, keys);
    hipLaunchKernelGGL(k_med0,   dim3(NB * PERIOD), dim3(256), 0, stream, keys, med0key);
    hipLaunchKernelGGL(k_edge,   dim3(NB * 6), dim3(256), 0, stream, keys, med0key, medBedge);
    hipLaunchKernelGGL(k_final,  dim3(NB * 4), dim3(64), 0, stream, med0key, medBedge, wsTab);
    hipLaunchKernelGGL(stl_outputs, dim3(K2GRID), dim3(NT), 0, stream, x, wsTab, out);
}